// Round 2
// baseline (4544.020 us; speedup 1.0000x reference)
//
#include <hip/hip_runtime.h>
#include <stddef.h>

#define NN 100000
#define NE 800000
#define DIN 128
#define DH 512
#define MPAD 100032   // 1563 * 64

// ---------------- CSR build ----------------

__global__ void k_count(const int* __restrict__ dst, int* __restrict__ cnt) {
  int i = blockIdx.x * blockDim.x + threadIdx.x;
  if (i < NE) atomicAdd(&cnt[dst[i]], 1);
}

__global__ void k_invdeg(const int* __restrict__ cnt, float* __restrict__ inv_deg) {
  int i = blockIdx.x * blockDim.x + threadIdx.x;
  if (i < NN) inv_deg[i] = 1.0f / (float)(cnt[i] > 1 ? cnt[i] : 1);
}

__global__ void k_scan1(const int* __restrict__ cnt, int* __restrict__ excl,
                        int* __restrict__ partials) {
  __shared__ int sh[256];
  int tid = threadIdx.x;
  int base = blockIdx.x * 1024 + tid * 4;
  int v[4]; int s = 0;
#pragma unroll
  for (int i = 0; i < 4; i++) { int idx = base + i; v[i] = (idx < NN) ? cnt[idx] : 0; s += v[i]; }
  sh[tid] = s; __syncthreads();
  for (int off = 1; off < 256; off <<= 1) {
    int t = (tid >= off) ? sh[tid - off] : 0;
    __syncthreads();
    sh[tid] += t;
    __syncthreads();
  }
  int run = sh[tid] - s;
#pragma unroll
  for (int i = 0; i < 4; i++) { int idx = base + i; if (idx < NN) excl[idx] = run; run += v[i]; }
  if (tid == 255) partials[blockIdx.x] = sh[255];
}

__global__ void k_scan2(int* __restrict__ partials, int* __restrict__ row_start, int nparts) {
  __shared__ int sh[128];
  int tid = threadIdx.x;
  int v = (tid < nparts) ? partials[tid] : 0;
  sh[tid] = v; __syncthreads();
  for (int off = 1; off < 128; off <<= 1) {
    int t = (tid >= off) ? sh[tid - off] : 0;
    __syncthreads();
    sh[tid] += t;
    __syncthreads();
  }
  if (tid < nparts) partials[tid] = sh[tid] - v;
  if (tid == 127) row_start[NN] = sh[127];
}

__global__ void k_scan3(int* __restrict__ excl, const int* __restrict__ partials) {
  int i = blockIdx.x * blockDim.x + threadIdx.x;
  if (i < NN) excl[i] += partials[i >> 10];
}

__global__ void k_fill(const int* __restrict__ src, const int* __restrict__ dst,
                       const int* __restrict__ row_start, int* __restrict__ cursor,
                       int* __restrict__ ssrc) {
  int i = blockIdx.x * blockDim.x + threadIdx.x;
  if (i < NE) {
    int d = dst[i];
    int pos = atomicAdd(&cursor[d], 1);
    ssrc[row_start[d] + pos] = src[i];
  }
}

// ---------------- mean aggregation (wave per node) ----------------

__global__ __launch_bounds__(256) void k_agg512(
    const float* __restrict__ z, const int* __restrict__ rs,
    const int* __restrict__ ssrc, const float* __restrict__ inv_deg,
    float* __restrict__ agg) {
  int w = (blockIdx.x * blockDim.x + threadIdx.x) >> 6;
  int lane = threadIdx.x & 63;
  if (w >= NN) return;
  int e0 = rs[w], e1 = rs[w + 1];
  float ax = 0, ay = 0, az = 0, aw = 0, bx = 0, by = 0, bz = 0, bw = 0;
  for (int e = e0; e < e1; ++e) {
    int s = ssrc[e];
    const float4* p = (const float4*)(z + (size_t)s * DH);
    float4 v0 = p[lane];
    float4 v1 = p[lane + 64];
    ax += v0.x; ay += v0.y; az += v0.z; aw += v0.w;
    bx += v1.x; by += v1.y; bz += v1.z; bw += v1.w;
  }
  float s0 = inv_deg[w];
  float4 o0 = {ax * s0, ay * s0, az * s0, aw * s0};
  float4 o1 = {bx * s0, by * s0, bz * s0, bw * s0};
  float4* q = (float4*)(agg + (size_t)w * DH);
  q[lane] = o0;
  q[lane + 64] = o1;
}

__global__ __launch_bounds__(256) void k_agg128(
    const float* __restrict__ z, const int* __restrict__ rs,
    const int* __restrict__ ssrc, const float* __restrict__ inv_deg,
    float* __restrict__ agg) {
  int w = (blockIdx.x * blockDim.x + threadIdx.x) >> 6;
  int lane = threadIdx.x & 63;
  if (w >= NN) return;
  int e0 = rs[w], e1 = rs[w + 1];
  float ax = 0, ay = 0;
  for (int e = e0; e < e1; ++e) {
    int s = ssrc[e];
    const float2* p = (const float2*)(z + (size_t)s * DIN);
    float2 v = p[lane];
    ax += v.x; ay += v.y;
  }
  float s0 = inv_deg[w];
  float2 o = {ax * s0, ay * s0};
  ((float2*)(agg + (size_t)w * DIN))[lane] = o;
}

// ---------------- fused GEMM: out = act(A1@W1^T [+ A2@W2^T] + b [+ add1 [+ add2]]) ----------------

template <bool PRELU, bool HASA2, int NADD>
__global__ __launch_bounds__(256) void k_gemm(
    const float* __restrict__ A1, const float* __restrict__ W1, int K1,
    const float* __restrict__ A2, const float* __restrict__ W2, int K2,
    const float* __restrict__ bias,
    const float* __restrict__ add1, const float* __restrict__ add2,
    const float* __restrict__ aptr, float* __restrict__ out) {
  __shared__ float As[32][68];
  __shared__ float Bs[32][68];
  const int m0 = blockIdx.x * 64, n0 = blockIdx.y * 64;
  const int tid = threadIdx.x;
  const int tm = (tid >> 4) * 4, tn = (tid & 15) * 4;
  float acc[4][4];
#pragma unroll
  for (int i = 0; i < 4; i++)
#pragma unroll
    for (int j = 0; j < 4; j++) acc[i][j] = 0.f;

  const int r = tid >> 3;        // 0..31
  const int c = (tid & 7) * 4;   // 0,4,..,28

  const int npass = HASA2 ? 2 : 1;
  for (int pass = 0; pass < npass; ++pass) {
    const float* A = pass ? A2 : A1;
    const float* W = pass ? W2 : W1;
    const int K = pass ? K2 : K1;
    for (int k0 = 0; k0 < K; k0 += 32) {
#pragma unroll
      for (int h = 0; h < 2; ++h) {
        int row = r + h * 32;
        int mrow = m0 + row;
        if (mrow >= NN) mrow = NN - 1;  // clamp: padded rows discarded at store
        const float4 va = *(const float4*)(A + (size_t)mrow * K + (k0 + c));
        As[c + 0][row] = va.x; As[c + 1][row] = va.y;
        As[c + 2][row] = va.z; As[c + 3][row] = va.w;
        const float4 vb = *(const float4*)(W + (size_t)(n0 + row) * K + (k0 + c));
        Bs[c + 0][row] = vb.x; Bs[c + 1][row] = vb.y;
        Bs[c + 2][row] = vb.z; Bs[c + 3][row] = vb.w;
      }
      __syncthreads();
#pragma unroll
      for (int k = 0; k < 32; ++k) {
        const float4 a4 = *(const float4*)&As[k][tm];
        const float4 b4 = *(const float4*)&Bs[k][tn];
        const float av[4] = {a4.x, a4.y, a4.z, a4.w};
        const float bv[4] = {b4.x, b4.y, b4.z, b4.w};
#pragma unroll
        for (int i = 0; i < 4; i++)
#pragma unroll
          for (int j = 0; j < 4; j++) acc[i][j] += av[i] * bv[j];
      }
      __syncthreads();
    }
  }

  const float aval = PRELU ? aptr[0] : 0.f;
#pragma unroll
  for (int i = 0; i < 4; i++) {
    int m = m0 + tm + i;
    if (m >= NN) continue;
    float v[4];
#pragma unroll
    for (int j = 0; j < 4; j++) v[j] = acc[i][j] + bias[n0 + tn + j];
    if constexpr (NADD >= 1) {
      const float4 e = *(const float4*)(add1 + (size_t)m * DH + n0 + tn);
      v[0] += e.x; v[1] += e.y; v[2] += e.z; v[3] += e.w;
    }
    if constexpr (NADD >= 2) {
      const float4 e = *(const float4*)(add2 + (size_t)m * DH + n0 + tn);
      v[0] += e.x; v[1] += e.y; v[2] += e.z; v[3] += e.w;
    }
    if constexpr (PRELU) {
#pragma unroll
      for (int j = 0; j < 4; j++) v[j] = v[j] > 0.f ? v[j] : aval * v[j];
    }
    float4 o; o.x = v[0]; o.y = v[1]; o.z = v[2]; o.w = v[3];
    *(float4*)(out + (size_t)m * DH + n0 + tn) = o;
  }
}

// ---------------- launch ----------------

extern "C" void kernel_launch(void* const* d_in, const int* in_sizes, int n_in,
                              void* d_out, int out_size, void* d_ws, size_t ws_size,
                              hipStream_t stream) {
  const float* x = (const float*)d_in[0];
  const int* ei = (const int*)d_in[1];     // int32 on device (harness converts)
  const float* Wl1 = (const float*)d_in[2];
  const float* bl1 = (const float*)d_in[3];
  const float* Wr1 = (const float*)d_in[4];
  const float* Wl2 = (const float*)d_in[5];
  const float* bl2 = (const float*)d_in[6];
  const float* Wr2 = (const float*)d_in[7];
  const float* Wl3 = (const float*)d_in[8];
  const float* bl3 = (const float*)d_in[9];
  const float* Wr3 = (const float*)d_in[10];
  const float* Ww  = (const float*)d_in[11];
  const float* bw  = (const float*)d_in[12];
  const float* Ww2 = (const float*)d_in[13];
  const float* bw2 = (const float*)d_in[14];
  const float* ap  = (const float*)d_in[15];
  float* out = (float*)d_out;

  char* w = (char*)d_ws;
  size_t off = 0;
  float* h1 = (float*)(w + off); off += (size_t)MPAD * DH * 4;   // B0: h1
  float* zb = (float*)(w + off); off += (size_t)MPAD * DH * 4;   // B1: ag1 / z2 / z3
  float* ag = (float*)(w + off); off += (size_t)MPAD * DH * 4;   // B2: ag2 / ag3
  float* h2 = out;                                               // d_out doubles as h2 scratch
  float* inv_deg = (float*)(w + off); off += (size_t)NN * 4;
  int* row_start = (int*)(w + off); off += (size_t)(NN + 1) * 4;
  int* cursor = (int*)(w + off); off += (size_t)NN * 4;
  int* ssrc = (int*)(w + off); off += (size_t)NE * 4;
  int* partials = (int*)(w + off); off += 512;

  const int* esrc = ei;
  const int* edst = ei + NE;

  // CSR build (once, reused by all 3 layers)
  hipMemsetAsync(cursor, 0, NN * 4, stream);
  k_count<<<(NE + 255) / 256, 256, 0, stream>>>(edst, cursor);
  k_invdeg<<<(NN + 255) / 256, 256, 0, stream>>>(cursor, inv_deg);
  k_scan1<<<(NN + 1023) / 1024, 256, 0, stream>>>(cursor, row_start, partials);
  k_scan2<<<1, 128, 0, stream>>>(partials, row_start, (NN + 1023) / 1024);
  k_scan3<<<(NN + 255) / 256, 256, 0, stream>>>(row_start, partials);
  hipMemsetAsync(cursor, 0, NN * 4, stream);
  k_fill<<<(NE + 255) / 256, 256, 0, stream>>>(esrc, edst, row_start, cursor, ssrc);

  dim3 gg(MPAD / 64, 8);

  // Layer 1: ag1 = agg(x) (in zb); h1 = prelu(ag1@Wl1^T + bl1 + x@Wr1^T)
  k_agg128<<<(NN + 3) / 4, 256, 0, stream>>>(x, row_start, ssrc, inv_deg, zb);
  k_gemm<true, true, 0><<<gg, 256, 0, stream>>>(zb, Wl1, DIN, x, Wr1, DIN, bl1,
                                                nullptr, nullptr, ap, h1);
  // z2 = h1 + x@Ww^T + bw  (into zb; gemm doesn't read zb)
  k_gemm<false, false, 1><<<gg, 256, 0, stream>>>(x, Ww, DIN, nullptr, nullptr, 0, bw,
                                                  h1, nullptr, nullptr, zb);
  // Layer 2: ag2 = agg(z2); h2 = prelu(ag2@Wl2^T + bl2 + z2@Wr2^T)   (h2 in d_out)
  k_agg512<<<(NN + 3) / 4, 256, 0, stream>>>(zb, row_start, ssrc, inv_deg, ag);
  k_gemm<true, true, 0><<<gg, 256, 0, stream>>>(ag, Wl2, DH, zb, Wr2, DH, bl2,
                                                nullptr, nullptr, ap, h2);
  // z3 = h2 + h1 + x@Ww2^T + bw2  (into zb)
  k_gemm<false, false, 2><<<gg, 256, 0, stream>>>(x, Ww2, DIN, nullptr, nullptr, 0, bw2,
                                                  h2, h1, nullptr, zb);
  // Layer 3: ag3 = agg(z3); out = prelu(ag3@Wl3^T + bl3 + z3@Wr3^T) -> d_out
  k_agg512<<<(NN + 3) / 4, 256, 0, stream>>>(zb, row_start, ssrc, inv_deg, ag);
  k_gemm<true, true, 0><<<gg, 256, 0, stream>>>(ag, Wl3, DH, zb, Wr3, DH, bl3,
                                                nullptr, nullptr, ap, out);
}

// Round 3
// 1362.037 us; speedup vs baseline: 3.3362x; 3.3362x over previous
//
#include <hip/hip_runtime.h>
#include <stddef.h>

#define NN 100000
#define NE 800000
#define DIN 128
#define DH 512
#define MT 782   // ceil(100000/128)

typedef __attribute__((ext_vector_type(8))) short sh8;
typedef __attribute__((ext_vector_type(4))) float f32x4;

__device__ __forceinline__ unsigned short f2b(float f) {
  unsigned u = __float_as_uint(f);
  return (unsigned short)((u + 0x7FFFu + ((u >> 16) & 1u)) >> 16);
}
__device__ __forceinline__ float b2f(unsigned short s) {
  return __uint_as_float(((unsigned)s) << 16);
}

// ---------------- CSR build ----------------

__global__ void k_count(const int* __restrict__ dst, int* __restrict__ cnt) {
  int i = blockIdx.x * blockDim.x + threadIdx.x;
  if (i < NE) atomicAdd(&cnt[dst[i]], 1);
}

__global__ void k_invdeg(const int* __restrict__ cnt, float* __restrict__ inv_deg) {
  int i = blockIdx.x * blockDim.x + threadIdx.x;
  if (i < NN) inv_deg[i] = 1.0f / (float)(cnt[i] > 1 ? cnt[i] : 1);
}

__global__ void k_scan1(const int* __restrict__ cnt, int* __restrict__ excl,
                        int* __restrict__ partials) {
  __shared__ int sh[256];
  int tid = threadIdx.x;
  int base = blockIdx.x * 1024 + tid * 4;
  int v[4]; int s = 0;
#pragma unroll
  for (int i = 0; i < 4; i++) { int idx = base + i; v[i] = (idx < NN) ? cnt[idx] : 0; s += v[i]; }
  sh[tid] = s; __syncthreads();
  for (int off = 1; off < 256; off <<= 1) {
    int t = (tid >= off) ? sh[tid - off] : 0;
    __syncthreads();
    sh[tid] += t;
    __syncthreads();
  }
  int run = sh[tid] - s;
#pragma unroll
  for (int i = 0; i < 4; i++) { int idx = base + i; if (idx < NN) excl[idx] = run; run += v[i]; }
  if (tid == 255) partials[blockIdx.x] = sh[255];
}

__global__ void k_scan2(int* __restrict__ partials, int* __restrict__ row_start, int nparts) {
  __shared__ int sh[128];
  int tid = threadIdx.x;
  int v = (tid < nparts) ? partials[tid] : 0;
  sh[tid] = v; __syncthreads();
  for (int off = 1; off < 128; off <<= 1) {
    int t = (tid >= off) ? sh[tid - off] : 0;
    __syncthreads();
    sh[tid] += t;
    __syncthreads();
  }
  if (tid < nparts) partials[tid] = sh[tid] - v;
  if (tid == 127) row_start[NN] = sh[127];
}

__global__ void k_scan3(int* __restrict__ excl, const int* __restrict__ partials) {
  int i = blockIdx.x * blockDim.x + threadIdx.x;
  if (i < NN) excl[i] += partials[i >> 10];
}

__global__ void k_fill(const int* __restrict__ src, const int* __restrict__ dst,
                       const int* __restrict__ row_start, int* __restrict__ cursor,
                       int* __restrict__ ssrc) {
  int i = blockIdx.x * blockDim.x + threadIdx.x;
  if (i < NE) {
    int d = dst[i];
    int pos = atomicAdd(&cursor[d], 1);
    ssrc[row_start[d] + pos] = src[i];
  }
}

// ---------------- f32 -> bf16 convert ----------------

__global__ void k_f2b(const float* __restrict__ src, unsigned short* __restrict__ dst, int n) {
  int i = (blockIdx.x * blockDim.x + threadIdx.x) * 4;
  if (i < n) {
    float4 v = *(const float4*)(src + i);
    ushort4 o;
    o.x = f2b(v.x); o.y = f2b(v.y); o.z = f2b(v.z); o.w = f2b(v.w);
    *(ushort4*)(dst + i) = o;
  }
}

// ---------------- mean aggregation (wave per node, bf16 in/out, f32 accum) ----------------

__global__ __launch_bounds__(256) void k_aggb512(
    const unsigned short* __restrict__ z, const int* __restrict__ rs,
    const int* __restrict__ ssrc, const float* __restrict__ inv_deg,
    unsigned short* __restrict__ agg) {
  int w = (blockIdx.x * blockDim.x + threadIdx.x) >> 6;
  int lane = threadIdx.x & 63;
  if (w >= NN) return;
  int e0 = rs[w], e1 = rs[w + 1];
  float acc[8] = {0, 0, 0, 0, 0, 0, 0, 0};
  for (int e = e0; e < e1; ++e) {
    int s = ssrc[e];
    sh8 v = *(const sh8*)(z + (size_t)s * DH + lane * 8);
#pragma unroll
    for (int j = 0; j < 8; ++j) acc[j] += b2f((unsigned short)v[j]);
  }
  float s0 = inv_deg[w];
  sh8 o;
#pragma unroll
  for (int j = 0; j < 8; ++j) o[j] = (short)f2b(acc[j] * s0);
  *(sh8*)(agg + (size_t)w * DH + lane * 8) = o;
}

__global__ __launch_bounds__(256) void k_aggb128(
    const unsigned short* __restrict__ z, const int* __restrict__ rs,
    const int* __restrict__ ssrc, const float* __restrict__ inv_deg,
    unsigned short* __restrict__ agg) {
  int w = (blockIdx.x * blockDim.x + threadIdx.x) >> 6;
  int lane = threadIdx.x & 63;
  if (w >= NN) return;
  int e0 = rs[w], e1 = rs[w + 1];
  float a0 = 0.f, a1 = 0.f;
  for (int e = e0; e < e1; ++e) {
    int s = ssrc[e];
    unsigned v = *(const unsigned*)(z + (size_t)s * DIN + lane * 2);
    a0 += b2f((unsigned short)(v & 0xFFFFu));
    a1 += b2f((unsigned short)(v >> 16));
  }
  float s0 = inv_deg[w];
  unsigned o = (unsigned)f2b(a0 * s0) | ((unsigned)f2b(a1 * s0) << 16);
  *(unsigned*)(agg + (size_t)w * DIN + lane * 2) = o;
}

// ---------------- bf16 MFMA GEMM ----------------
// out = act(A1@W1^T [+ A2@W2^T] + bias [+ add1 [+ add2]])
// A: [M][K] bf16 row-major; W: [N][K] bf16 row-major (i.e. B^T). 128x128 tile, BK=32.

template <bool PRELU, bool HASA2, int NADD, bool OUTBF16>
__global__ __launch_bounds__(256) void k_mgemm(
    const unsigned short* __restrict__ A1, const unsigned short* __restrict__ W1, int K1,
    const unsigned short* __restrict__ A2, const unsigned short* __restrict__ W2, int K2,
    const float* __restrict__ bias, const float* __restrict__ add1,
    const float* __restrict__ add2, const float* __restrict__ aptr,
    void* __restrict__ outp) {
  __shared__ __align__(16) unsigned short As[128 * 32];
  __shared__ __align__(16) unsigned short Bs[128 * 32];
  const int tid = threadIdx.x;
  const int m0 = blockIdx.x * 128, n0 = blockIdx.y * 128;
  const int wid = tid >> 6, lane = tid & 63;
  const int r16 = lane & 15, kg = lane >> 4;
  const int wr = (wid >> 1) * 64, wc = (wid & 1) * 64;
  const int rA = tid >> 2;        // 0..63
  const int cA = (tid & 3) * 8;   // k-element offset

  f32x4 acc[4][4];
#pragma unroll
  for (int i = 0; i < 4; ++i)
#pragma unroll
    for (int j = 0; j < 4; ++j) acc[i][j] = 0.f;

  const int nsteps = (HASA2 ? (K1 + K2) : K1) / 32;

  auto ldA = [&](int s, int r) -> sh8 {
    int kk = s * 32;
    const unsigned short* A = A1; int K = K1;
    if (HASA2 && kk >= K1) { A = A2; K = K2; kk -= K1; }
    int row = m0 + r; if (row >= NN) row = NN - 1;  // clamp; padded rows dropped at store
    return *(const sh8*)(A + (size_t)row * K + kk + cA);
  };
  auto ldB = [&](int s, int r) -> sh8 {
    int kk = s * 32;
    const unsigned short* W = W1; int K = K1;
    if (HASA2 && kk >= K1) { W = W2; K = K2; kk -= K1; }
    return *(const sh8*)(W + (size_t)(n0 + r) * K + kk + cA);
  };

  sh8 va0 = ldA(0, rA), va1 = ldA(0, rA + 64);
  sh8 vb0 = ldB(0, rA), vb1 = ldB(0, rA + 64);

  for (int s = 0; s < nsteps; ++s) {
    __syncthreads();
    *(sh8*)&As[rA * 32 + cA] = va0;
    *(sh8*)&As[(rA + 64) * 32 + cA] = va1;
    *(sh8*)&Bs[rA * 32 + cA] = vb0;
    *(sh8*)&Bs[(rA + 64) * 32 + cA] = vb1;
    __syncthreads();
    if (s + 1 < nsteps) {  // prefetch next tile into regs, overlaps MFMA below
      va0 = ldA(s + 1, rA); va1 = ldA(s + 1, rA + 64);
      vb0 = ldB(s + 1, rA); vb1 = ldB(s + 1, rA + 64);
    }
    sh8 af[4], bfr[4];
#pragma unroll
    for (int i = 0; i < 4; ++i)
      af[i] = *(const sh8*)&As[(wr + i * 16 + r16) * 32 + kg * 8];
#pragma unroll
    for (int j = 0; j < 4; ++j)
      bfr[j] = *(const sh8*)&Bs[(wc + j * 16 + r16) * 32 + kg * 8];
#pragma unroll
    for (int i = 0; i < 4; ++i)
#pragma unroll
      for (int j = 0; j < 4; ++j)
        acc[i][j] = __builtin_amdgcn_mfma_f32_16x16x32_bf16(af[i], bfr[j], acc[i][j], 0, 0, 0);
  }

  const float aval = PRELU ? aptr[0] : 0.f;
  float* outf = (float*)outp;
  unsigned short* outb = (unsigned short*)outp;
#pragma unroll
  for (int i = 0; i < 4; ++i) {
    const int mbase = m0 + wr + i * 16 + kg * 4;
#pragma unroll
    for (int j = 0; j < 4; ++j) {
      const int col = n0 + wc + j * 16 + r16;
      const float bv = bias[col];
#pragma unroll
      for (int r = 0; r < 4; ++r) {
        const int m = mbase + r;
        if (m >= NN) continue;
        float t = acc[i][j][r] + bv;
        if constexpr (NADD >= 1) t += add1[(size_t)m * DH + col];
        if constexpr (NADD >= 2) t += add2[(size_t)m * DH + col];
        if constexpr (PRELU) t = t > 0.f ? t : aval * t;
        if constexpr (OUTBF16) outb[(size_t)m * DH + col] = f2b(t);
        else outf[(size_t)m * DH + col] = t;
      }
    }
  }
}

// ---------------- launch ----------------

extern "C" void kernel_launch(void* const* d_in, const int* in_sizes, int n_in,
                              void* d_out, int out_size, void* d_ws, size_t ws_size,
                              hipStream_t stream) {
  const float* x = (const float*)d_in[0];
  const int* ei = (const int*)d_in[1];
  const float* Wl1 = (const float*)d_in[2];
  const float* bl1 = (const float*)d_in[3];
  const float* Wr1 = (const float*)d_in[4];
  const float* Wl2 = (const float*)d_in[5];
  const float* bl2 = (const float*)d_in[6];
  const float* Wr2 = (const float*)d_in[7];
  const float* Wl3 = (const float*)d_in[8];
  const float* bl3 = (const float*)d_in[9];
  const float* Wr3 = (const float*)d_in[10];
  const float* Ww  = (const float*)d_in[11];
  const float* bw  = (const float*)d_in[12];
  const float* Ww2 = (const float*)d_in[13];
  const float* bw2 = (const float*)d_in[14];
  const float* ap  = (const float*)d_in[15];
  float* out = (float*)d_out;

  const size_t MP = 100096;  // 782*128
  char* w = (char*)d_ws;
  size_t off = 0;
  float* h1 = (float*)(w + off); off += MP * DH * 4;                 // 205 MB
  unsigned short* agb = (unsigned short*)(w + off); off += MP * DH * 2;  // 102.5 MB
  unsigned short* zb  = (unsigned short*)(w + off); off += MP * DH * 2;  // 102.5 MB
  unsigned short* xb  = (unsigned short*)(w + off); off += MP * DIN * 2; // 25.6 MB
  unsigned short* Wl1b = (unsigned short*)(w + off); off += (size_t)DH * DIN * 2;
  unsigned short* Wr1b = (unsigned short*)(w + off); off += (size_t)DH * DIN * 2;
  unsigned short* Wwb  = (unsigned short*)(w + off); off += (size_t)DH * DIN * 2;
  unsigned short* Ww2b = (unsigned short*)(w + off); off += (size_t)DH * DIN * 2;
  unsigned short* Wl2b = (unsigned short*)(w + off); off += (size_t)DH * DH * 2;
  unsigned short* Wr2b = (unsigned short*)(w + off); off += (size_t)DH * DH * 2;
  unsigned short* Wl3b = (unsigned short*)(w + off); off += (size_t)DH * DH * 2;
  unsigned short* Wr3b = (unsigned short*)(w + off); off += (size_t)DH * DH * 2;
  float* inv_deg = (float*)(w + off); off += (size_t)NN * 4;
  int* row_start = (int*)(w + off); off += (size_t)(NN + 1) * 4;
  int* cursor = (int*)(w + off); off += (size_t)NN * 4;
  int* ssrc = (int*)(w + off); off += (size_t)NE * 4;
  int* partials = (int*)(w + off); off += 512;

  const int* esrc = ei;
  const int* edst = ei + NE;
  float* h2 = out;  // d_out doubles as f32 h2 scratch

  // CSR build (once, reused by all 3 layers)
  hipMemsetAsync(cursor, 0, NN * 4, stream);
  k_count<<<(NE + 255) / 256, 256, 0, stream>>>(edst, cursor);
  k_invdeg<<<(NN + 255) / 256, 256, 0, stream>>>(cursor, inv_deg);
  k_scan1<<<(NN + 1023) / 1024, 256, 0, stream>>>(cursor, row_start, partials);
  k_scan2<<<1, 128, 0, stream>>>(partials, row_start, (NN + 1023) / 1024);
  k_scan3<<<(NN + 255) / 256, 256, 0, stream>>>(row_start, partials);
  hipMemsetAsync(cursor, 0, NN * 4, stream);
  k_fill<<<(NE + 255) / 256, 256, 0, stream>>>(esrc, edst, row_start, cursor, ssrc);

  // bf16 conversions
  const int WK = DH * DIN;   // 65536
  const int WB = DH * DH;    // 262144
  k_f2b<<<(WK / 4 + 255) / 256, 256, 0, stream>>>(Wl1, Wl1b, WK);
  k_f2b<<<(WK / 4 + 255) / 256, 256, 0, stream>>>(Wr1, Wr1b, WK);
  k_f2b<<<(WK / 4 + 255) / 256, 256, 0, stream>>>(Ww,  Wwb,  WK);
  k_f2b<<<(WK / 4 + 255) / 256, 256, 0, stream>>>(Ww2, Ww2b, WK);
  k_f2b<<<(WB / 4 + 255) / 256, 256, 0, stream>>>(Wl2, Wl2b, WB);
  k_f2b<<<(WB / 4 + 255) / 256, 256, 0, stream>>>(Wr2, Wr2b, WB);
  k_f2b<<<(WB / 4 + 255) / 256, 256, 0, stream>>>(Wl3, Wl3b, WB);
  k_f2b<<<(WB / 4 + 255) / 256, 256, 0, stream>>>(Wr3, Wr3b, WB);
  k_f2b<<<(NN * DIN / 4 + 255) / 256, 256, 0, stream>>>(x, xb, NN * DIN);

  dim3 gg(MT, 4);

  // Layer 1: ag1 = agg(xb) -> agb (stride 128); h1 = prelu(ag1@Wl1^T + bl1 + xb@Wr1^T) [f32]
  k_aggb128<<<(NN + 3) / 4, 256, 0, stream>>>(xb, row_start, ssrc, inv_deg, agb);
  k_mgemm<true, true, 0, false><<<gg, 256, 0, stream>>>(
      agb, Wl1b, DIN, xb, Wr1b, DIN, bl1, nullptr, nullptr, ap, h1);
  // z2 = xb@Ww^T + bw + h1 -> zb (bf16)
  k_mgemm<false, false, 1, true><<<gg, 256, 0, stream>>>(
      xb, Wwb, DIN, nullptr, nullptr, 0, bw, h1, nullptr, nullptr, zb);
  // Layer 2: ag2 = agg(z2); h2 = prelu(ag2@Wl2^T + bl2 + z2@Wr2^T) [f32, in d_out]
  k_aggb512<<<(NN + 3) / 4, 256, 0, stream>>>(zb, row_start, ssrc, inv_deg, agb);
  k_mgemm<true, true, 0, false><<<gg, 256, 0, stream>>>(
      agb, Wl2b, DH, zb, Wr2b, DH, bl2, nullptr, nullptr, ap, h2);
  // z3 = xb@Ww2^T + bw2 + h2 + h1 -> zb (bf16)
  k_mgemm<false, false, 2, true><<<gg, 256, 0, stream>>>(
      xb, Ww2b, DIN, nullptr, nullptr, 0, bw2, h2, h1, nullptr, zb);
  // Layer 3: ag3 = agg(z3); out = prelu(ag3@Wl3^T + bl3 + z3@Wr3^T) -> d_out (f32)
  k_aggb512<<<(NN + 3) / 4, 256, 0, stream>>>(zb, row_start, ssrc, inv_deg, agb);
  k_mgemm<true, true, 0, false><<<gg, 256, 0, stream>>>(
      agb, Wl3b, DH, zb, Wr3b, DH, bl3, nullptr, nullptr, ap, out);
}

// Round 4
// 1065.559 us; speedup vs baseline: 4.2644x; 1.2782x over previous
//
#include <hip/hip_runtime.h>
#include <stddef.h>

#define NN 100000
#define NE 800000
#define DIN 128
#define DH 512
#define MT 782   // ceil(100000/128)

typedef __attribute__((ext_vector_type(8))) short sh8;
typedef __attribute__((ext_vector_type(4))) float f32x4;

__device__ __forceinline__ unsigned short f2b(float f) {
  unsigned u = __float_as_uint(f);
  return (unsigned short)((u + 0x7FFFu + ((u >> 16) & 1u)) >> 16);
}
__device__ __forceinline__ float b2f(unsigned short s) {
  return __uint_as_float(((unsigned)s) << 16);
}

__device__ __forceinline__ void gload16(const unsigned short* g, unsigned short* l) {
  __builtin_amdgcn_global_load_lds(
      (const __attribute__((address_space(1))) void*)g,
      (__attribute__((address_space(3))) void*)l, 16, 0, 0);
}

// ---------------- CSR build ----------------

__global__ void k_count(const int* __restrict__ dst, int* __restrict__ cnt) {
  int i = blockIdx.x * blockDim.x + threadIdx.x;
  if (i < NE) atomicAdd(&cnt[dst[i]], 1);
}

__global__ void k_invdeg(const int* __restrict__ cnt, float* __restrict__ inv_deg) {
  int i = blockIdx.x * blockDim.x + threadIdx.x;
  if (i < NN) inv_deg[i] = 1.0f / (float)(cnt[i] > 1 ? cnt[i] : 1);
}

__global__ void k_scan1(const int* __restrict__ cnt, int* __restrict__ excl,
                        int* __restrict__ partials) {
  __shared__ int sh[256];
  int tid = threadIdx.x;
  int base = blockIdx.x * 1024 + tid * 4;
  int v[4]; int s = 0;
#pragma unroll
  for (int i = 0; i < 4; i++) { int idx = base + i; v[i] = (idx < NN) ? cnt[idx] : 0; s += v[i]; }
  sh[tid] = s; __syncthreads();
  for (int off = 1; off < 256; off <<= 1) {
    int t = (tid >= off) ? sh[tid - off] : 0;
    __syncthreads();
    sh[tid] += t;
    __syncthreads();
  }
  int run = sh[tid] - s;
#pragma unroll
  for (int i = 0; i < 4; i++) { int idx = base + i; if (idx < NN) excl[idx] = run; run += v[i]; }
  if (tid == 255) partials[blockIdx.x] = sh[255];
}

__global__ void k_scan2(int* __restrict__ partials, int* __restrict__ row_start, int nparts) {
  __shared__ int sh[128];
  int tid = threadIdx.x;
  int v = (tid < nparts) ? partials[tid] : 0;
  sh[tid] = v; __syncthreads();
  for (int off = 1; off < 128; off <<= 1) {
    int t = (tid >= off) ? sh[tid - off] : 0;
    __syncthreads();
    sh[tid] += t;
    __syncthreads();
  }
  if (tid < nparts) partials[tid] = sh[tid] - v;
  if (tid == 127) row_start[NN] = sh[127];
}

__global__ void k_scan3(int* __restrict__ excl, const int* __restrict__ partials) {
  int i = blockIdx.x * blockDim.x + threadIdx.x;
  if (i < NN) excl[i] += partials[i >> 10];
}

__global__ void k_fill(const int* __restrict__ src, const int* __restrict__ dst,
                       const int* __restrict__ row_start, int* __restrict__ cursor,
                       int* __restrict__ ssrc) {
  int i = blockIdx.x * blockDim.x + threadIdx.x;
  if (i < NE) {
    int d = dst[i];
    int pos = atomicAdd(&cursor[d], 1);
    ssrc[row_start[d] + pos] = src[i];
  }
}

// ---------------- f32 -> bf16 convert ----------------

__global__ void k_f2b(const float* __restrict__ src, unsigned short* __restrict__ dst, int n) {
  int i = (blockIdx.x * blockDim.x + threadIdx.x) * 4;
  if (i < n) {
    float4 v = *(const float4*)(src + i);
    ushort4 o;
    o.x = f2b(v.x); o.y = f2b(v.y); o.z = f2b(v.z); o.w = f2b(v.w);
    *(ushort4*)(dst + i) = o;
  }
}

// ---------------- mean aggregation (wave per node, bf16 in/out, f32 accum) ----------------

__global__ __launch_bounds__(256) void k_aggb512(
    const unsigned short* __restrict__ z, const int* __restrict__ rs,
    const int* __restrict__ ssrc, const float* __restrict__ inv_deg,
    unsigned short* __restrict__ agg) {
  int w = (blockIdx.x * blockDim.x + threadIdx.x) >> 6;
  int lane = threadIdx.x & 63;
  if (w >= NN) return;
  int e0 = rs[w], e1 = rs[w + 1];
  float acc[8] = {0, 0, 0, 0, 0, 0, 0, 0};
  for (int e = e0; e < e1; ++e) {
    int s = ssrc[e];
    sh8 v = *(const sh8*)(z + (size_t)s * DH + lane * 8);
#pragma unroll
    for (int j = 0; j < 8; ++j) acc[j] += b2f((unsigned short)v[j]);
  }
  float s0 = inv_deg[w];
  sh8 o;
#pragma unroll
  for (int j = 0; j < 8; ++j) o[j] = (short)f2b(acc[j] * s0);
  *(sh8*)(agg + (size_t)w * DH + lane * 8) = o;
}

__global__ __launch_bounds__(256) void k_aggb128(
    const unsigned short* __restrict__ z, const int* __restrict__ rs,
    const int* __restrict__ ssrc, const float* __restrict__ inv_deg,
    unsigned short* __restrict__ agg) {
  int w = (blockIdx.x * blockDim.x + threadIdx.x) >> 6;
  int lane = threadIdx.x & 63;
  if (w >= NN) return;
  int e0 = rs[w], e1 = rs[w + 1];
  float a0 = 0.f, a1 = 0.f;
  for (int e = e0; e < e1; ++e) {
    int s = ssrc[e];
    unsigned v = *(const unsigned*)(z + (size_t)s * DIN + lane * 2);
    a0 += b2f((unsigned short)(v & 0xFFFFu));
    a1 += b2f((unsigned short)(v >> 16));
  }
  float s0 = inv_deg[w];
  unsigned o = (unsigned)f2b(a0 * s0) | ((unsigned)f2b(a1 * s0) << 16);
  *(unsigned*)(agg + (size_t)w * DIN + lane * 2) = o;
}

// ---------------- MFMA GEMM building blocks ----------------
// Tile 128x128, BK=32, 256 thr (4 waves, 2x2 of 64x64). LDS [row][32] bf16,
// lane-linear so global_load_lds DMA staging applies directly.

__device__ __forceinline__ void stage_tile(
    unsigned short* ldsA, unsigned short* ldsB,
    const unsigned short* __restrict__ A, int sA, int m0,
    const unsigned short* __restrict__ B, int sB, int n0,
    int k0, int tid) {
  const int w = tid >> 6, l = tid & 63;
  const int kc = (l & 3) * 8;
  const int rsub = l >> 2;
#pragma unroll
  for (int i = 0; i < 2; ++i) {
    int rl = w * 32 + i * 16 + rsub;
    int ra = m0 + rl; if (ra >= NN) ra = NN - 1;   // clamp; padded rows dropped at store
    gload16(A + (size_t)ra * sA + k0 + kc, ldsA + (size_t)(w * 32 + i * 16) * 32);
    gload16(B + (size_t)(n0 + rl) * sB + k0 + kc, ldsB + (size_t)(w * 32 + i * 16) * 32);
  }
}

__device__ __forceinline__ void mfma_step(
    const unsigned short* As, const unsigned short* Bs,
    int wr, int wc, int r16, int kg, f32x4 (&acc)[4][4]) {
  sh8 af[4], bf[4];
#pragma unroll
  for (int i = 0; i < 4; ++i)
    af[i] = *(const sh8*)&As[(wr + i * 16 + r16) * 32 + kg * 8];
#pragma unroll
  for (int j = 0; j < 4; ++j)
    bf[j] = *(const sh8*)&Bs[(wc + j * 16 + r16) * 32 + kg * 8];
#pragma unroll
  for (int i = 0; i < 4; ++i)
#pragma unroll
    for (int j = 0; j < 4; ++j)
      acc[i][j] = __builtin_amdgcn_mfma_f32_16x16x32_bf16(af[i], bf[j], acc[i][j], 0, 0, 0);
}

// K1 fused: h1 = prelu(ag@Wl1^T + x@Wr1^T + bl1)  [register-only]
//           z2  = h1 + x@Ww^T  + bw   -> zb (bf16)
//           z3p = h1 + x@Ww2^T + bw2  -> z3pb (bf16)
__global__ __launch_bounds__(256, 2) void k_gemm1(
    const unsigned short* __restrict__ ag, const unsigned short* __restrict__ xb,
    const unsigned short* __restrict__ Wl1, const unsigned short* __restrict__ Wr1,
    const unsigned short* __restrict__ Ww, const unsigned short* __restrict__ Ww2,
    const float* __restrict__ bl1, const float* __restrict__ bw,
    const float* __restrict__ bw2, const float* __restrict__ aptr,
    unsigned short* __restrict__ z2o, unsigned short* __restrict__ z3po) {
  __shared__ __align__(16) unsigned short As[128 * 32];
  __shared__ __align__(16) unsigned short Bs[128 * 32];
  const int tid = threadIdx.x;
  const int m0 = blockIdx.x * 128, n0 = blockIdx.y * 128;
  const int wid = tid >> 6, lane = tid & 63;
  const int r16 = lane & 15, kg = lane >> 4;
  const int wr = (wid >> 1) * 64, wc = (wid & 1) * 64;

  f32x4 a0[4][4], a1[4][4], a2[4][4];
#pragma unroll
  for (int i = 0; i < 4; ++i)
#pragma unroll
    for (int j = 0; j < 4; ++j) { a0[i][j] = 0.f; a1[i][j] = 0.f; a2[i][j] = 0.f; }

  for (int s = 0; s < 16; ++s) {
    const int seg = s >> 2, k0 = (s & 3) * 32;
    const unsigned short* Ap = (seg == 0) ? ag : xb;
    const unsigned short* Bp = (seg == 0) ? Wl1 : (seg == 1) ? Wr1 : (seg == 2) ? Ww : Ww2;
    stage_tile(As, Bs, Ap, DIN, m0, Bp, DIN, n0, k0, tid);
    __syncthreads();
    if (seg <= 1)      mfma_step(As, Bs, wr, wc, r16, kg, a0);
    else if (seg == 2) mfma_step(As, Bs, wr, wc, r16, kg, a1);
    else               mfma_step(As, Bs, wr, wc, r16, kg, a2);
    __syncthreads();
  }

  const float aval = aptr[0];
#pragma unroll
  for (int i = 0; i < 4; ++i) {
    const int mbase = m0 + wr + i * 16 + kg * 4;
#pragma unroll
    for (int j = 0; j < 4; ++j) {
      const int col = n0 + wc + j * 16 + r16;
      const float b1 = bl1[col], b2 = bw[col], b3 = bw2[col];
#pragma unroll
      for (int r = 0; r < 4; ++r) {
        const int m = mbase + r;
        if (m >= NN) continue;
        float h1 = a0[i][j][r] + b1;
        h1 = h1 > 0.f ? h1 : aval * h1;
        z2o[(size_t)m * DH + col] = f2b(h1 + a1[i][j][r] + b2);
        z3po[(size_t)m * DH + col] = f2b(h1 + a2[i][j][r] + b3);
      }
    }
  }
}

// K2/K3: acc = Aag@Wl^T + Az@Wr^T (K=512+512); h = prelu(acc + bl)
//  LAST=false: out = h + z3p  -> bf16
//  LAST=true : out = h        -> f32
template <bool LAST>
__global__ __launch_bounds__(256, 4) void k_gemm23(
    const unsigned short* __restrict__ Aag, const unsigned short* __restrict__ Az,
    const unsigned short* __restrict__ Wl, const unsigned short* __restrict__ Wr,
    const float* __restrict__ bl, const float* __restrict__ aptr,
    const unsigned short* __restrict__ z3p, void* __restrict__ outp) {
  __shared__ __align__(16) unsigned short As[128 * 32];
  __shared__ __align__(16) unsigned short Bs[128 * 32];
  const int tid = threadIdx.x;
  const int m0 = blockIdx.x * 128, n0 = blockIdx.y * 128;
  const int wid = tid >> 6, lane = tid & 63;
  const int r16 = lane & 15, kg = lane >> 4;
  const int wr = (wid >> 1) * 64, wc = (wid & 1) * 64;

  f32x4 acc[4][4];
#pragma unroll
  for (int i = 0; i < 4; ++i)
#pragma unroll
    for (int j = 0; j < 4; ++j) acc[i][j] = 0.f;

  for (int s = 0; s < 32; ++s) {
    const int k0 = (s & 15) * 32;
    const unsigned short* Ap = (s < 16) ? Aag : Az;
    const unsigned short* Bp = (s < 16) ? Wl : Wr;
    stage_tile(As, Bs, Ap, DH, m0, Bp, DH, n0, k0, tid);
    __syncthreads();
    mfma_step(As, Bs, wr, wc, r16, kg, acc);
    __syncthreads();
  }

  const float aval = aptr[0];
  float* outf = (float*)outp;
  unsigned short* outb = (unsigned short*)outp;
#pragma unroll
  for (int i = 0; i < 4; ++i) {
    const int mbase = m0 + wr + i * 16 + kg * 4;
#pragma unroll
    for (int j = 0; j < 4; ++j) {
      const int col = n0 + wc + j * 16 + r16;
      const float bv = bl[col];
#pragma unroll
      for (int r = 0; r < 4; ++r) {
        const int m = mbase + r;
        if (m >= NN) continue;
        float h = acc[i][j][r] + bv;
        h = h > 0.f ? h : aval * h;
        if constexpr (LAST) {
          outf[(size_t)m * DH + col] = h;
        } else {
          outb[(size_t)m * DH + col] = f2b(h + b2f(z3p[(size_t)m * DH + col]));
        }
      }
    }
  }
}

// ---------------- launch ----------------

extern "C" void kernel_launch(void* const* d_in, const int* in_sizes, int n_in,
                              void* d_out, int out_size, void* d_ws, size_t ws_size,
                              hipStream_t stream) {
  const float* x = (const float*)d_in[0];
  const int* ei = (const int*)d_in[1];
  const float* Wl1 = (const float*)d_in[2];
  const float* bl1 = (const float*)d_in[3];
  const float* Wr1 = (const float*)d_in[4];
  const float* Wl2 = (const float*)d_in[5];
  const float* bl2 = (const float*)d_in[6];
  const float* Wr2 = (const float*)d_in[7];
  const float* Wl3 = (const float*)d_in[8];
  const float* bl3 = (const float*)d_in[9];
  const float* Wr3 = (const float*)d_in[10];
  const float* Ww  = (const float*)d_in[11];
  const float* bw  = (const float*)d_in[12];
  const float* Ww2 = (const float*)d_in[13];
  const float* bw2 = (const float*)d_in[14];
  const float* ap  = (const float*)d_in[15];
  float* out = (float*)d_out;

  const size_t MP = 100096;  // 782*128
  char* w = (char*)d_ws;
  size_t off = 0;
  unsigned short* xb   = (unsigned short*)(w + off); off += MP * DIN * 2;  // 25.6 MB
  unsigned short* ag1  = (unsigned short*)(w + off); off += MP * DIN * 2;  // 25.6 MB
  unsigned short* agb  = (unsigned short*)(w + off); off += MP * DH * 2;   // 102.5 MB
  unsigned short* zb   = (unsigned short*)(w + off); off += MP * DH * 2;   // 102.5 MB (z2)
  unsigned short* zc   = (unsigned short*)(w + off); off += MP * DH * 2;   // 102.5 MB (z3)
  unsigned short* z3pb = (unsigned short*)(w + off); off += MP * DH * 2;   // 102.5 MB
  unsigned short* Wl1b = (unsigned short*)(w + off); off += (size_t)DH * DIN * 2;
  unsigned short* Wr1b = (unsigned short*)(w + off); off += (size_t)DH * DIN * 2;
  unsigned short* Wwb  = (unsigned short*)(w + off); off += (size_t)DH * DIN * 2;
  unsigned short* Ww2b = (unsigned short*)(w + off); off += (size_t)DH * DIN * 2;
  unsigned short* Wl2b = (unsigned short*)(w + off); off += (size_t)DH * DH * 2;
  unsigned short* Wr2b = (unsigned short*)(w + off); off += (size_t)DH * DH * 2;
  unsigned short* Wl3b = (unsigned short*)(w + off); off += (size_t)DH * DH * 2;
  unsigned short* Wr3b = (unsigned short*)(w + off); off += (size_t)DH * DH * 2;
  float* inv_deg = (float*)(w + off); off += (size_t)NN * 4;
  int* row_start = (int*)(w + off); off += (size_t)(NN + 1) * 4;
  int* cursor = (int*)(w + off); off += (size_t)NN * 4;
  int* ssrc = (int*)(w + off); off += (size_t)NE * 4;
  int* partials = (int*)(w + off); off += 512;

  const int* esrc = ei;
  const int* edst = ei + NE;

  // CSR build (once, reused by all 3 layers)
  hipMemsetAsync(cursor, 0, NN * 4, stream);
  k_count<<<(NE + 255) / 256, 256, 0, stream>>>(edst, cursor);
  k_invdeg<<<(NN + 255) / 256, 256, 0, stream>>>(cursor, inv_deg);
  k_scan1<<<(NN + 1023) / 1024, 256, 0, stream>>>(cursor, row_start, partials);
  k_scan2<<<1, 128, 0, stream>>>(partials, row_start, (NN + 1023) / 1024);
  k_scan3<<<(NN + 255) / 256, 256, 0, stream>>>(row_start, partials);
  hipMemsetAsync(cursor, 0, NN * 4, stream);
  k_fill<<<(NE + 255) / 256, 256, 0, stream>>>(esrc, edst, row_start, cursor, ssrc);

  // bf16 conversions
  const int WK = DH * DIN;
  const int WB = DH * DH;
  k_f2b<<<(WK / 4 + 255) / 256, 256, 0, stream>>>(Wl1, Wl1b, WK);
  k_f2b<<<(WK / 4 + 255) / 256, 256, 0, stream>>>(Wr1, Wr1b, WK);
  k_f2b<<<(WK / 4 + 255) / 256, 256, 0, stream>>>(Ww,  Wwb,  WK);
  k_f2b<<<(WK / 4 + 255) / 256, 256, 0, stream>>>(Ww2, Ww2b, WK);
  k_f2b<<<(WB / 4 + 255) / 256, 256, 0, stream>>>(Wl2, Wl2b, WB);
  k_f2b<<<(WB / 4 + 255) / 256, 256, 0, stream>>>(Wr2, Wr2b, WB);
  k_f2b<<<(WB / 4 + 255) / 256, 256, 0, stream>>>(Wl3, Wl3b, WB);
  k_f2b<<<(WB / 4 + 255) / 256, 256, 0, stream>>>(Wr3, Wr3b, WB);
  k_f2b<<<(NN * DIN / 4 + 255) / 256, 256, 0, stream>>>(x, xb, NN * DIN);

  dim3 gg(MT, 4);

  // agg1 = mean(x) ; K1 fused -> z2 (zb), z3p (z3pb); h1 never materialized
  k_aggb128<<<(NN + 3) / 4, 256, 0, stream>>>(xb, row_start, ssrc, inv_deg, ag1);
  k_gemm1<<<gg, 256, 0, stream>>>(ag1, xb, Wl1b, Wr1b, Wwb, Ww2b, bl1, bw, bw2, ap,
                                  zb, z3pb);
  // layer 2: agg2 = mean(z2); z3 = prelu(agg2@Wl2 + z2@Wr2 + bl2) + z3p -> zc
  k_aggb512<<<(NN + 3) / 4, 256, 0, stream>>>(zb, row_start, ssrc, inv_deg, agb);
  k_gemm23<false><<<gg, 256, 0, stream>>>(agb, zb, Wl2b, Wr2b, bl2, ap, z3pb, zc);
  // layer 3: agg3 = mean(z3); out = prelu(agg3@Wl3 + z3@Wr3 + bl3) -> f32 d_out
  k_aggb512<<<(NN + 3) / 4, 256, 0, stream>>>(zc, row_start, ssrc, inv_deg, agb);
  k_gemm23<true><<<gg, 256, 0, stream>>>(agb, zc, Wl3b, Wr3b, bl3, ap, nullptr, out);
}